// Round 1
// baseline (238.708 us; speedup 1.0000x reference)
//
#include <hip/hip_runtime.h>
#include <hip/hip_fp16.h>

// Problem constants (fixed by setup_inputs): V=8192, F=256, B=32, L=64.
#define V_SIZE   8192
#define F_SIZE   256
#define F2       128            // half2 per feature row
#define B_SIZE   32
#define L_SIZE   64
#define NPAIR    2016           // B*(L-1)
#define NPAIR_PAD 2048
#define VCHUNK   128            // vocab rows per block (grid.y)
#define NCHUNK   (V_SIZE / VCHUNK)  // 64

// Math: nll = B*ln(V) + sum_pairs [ w0*(g(p) - g(tgt)) + ln(S_pair) ],
//   g(v)   = sum_f wf[f]*feat[v,f]*(2*prev_f - 1)   (row-constant terms of the
//            reference's `sim` cancel inside log_softmax)
//   S_pair = sum_v exp(w0*(g(v) - g(p)))            (g(p) is the EXACT max for wf>=0)

__device__ __forceinline__ __half2 u2h(unsigned u) {
    union { unsigned u; __half2 h; } c; c.u = u; return c.h;
}
__device__ __forceinline__ float h2lo(__half2 h) { return __half2float(__low2half(h)); }
__device__ __forceinline__ float h2hi(__half2 h) { return __half2float(__high2half(h)); }

// ---------------- prep: featw[v,f] = (half)(wf[f] * feat[v,f]) --------------
__global__ __launch_bounds__(256) void prep_kernel(
    const float* __restrict__ weights,     // 257 floats, wf = weights[1:]
    const int*   __restrict__ features,    // V*F ints in {0,1}
    __half2*     __restrict__ featw) {
    int idx = blockIdx.x * 256 + threadIdx.x;      // 0 .. V*F2-1
    int j = idx & (F2 - 1);                        // half2 index within row
    const int2* f2 = (const int2*)features;
    int2 q = f2[idx];                              // features[v*256+2j], [..+2j+1]
    float w0 = weights[1 + 2 * j];
    float w1 = weights[2 + 2 * j];
    __half2 h;
    h.x = __float2half(w0 * (float)q.x);
    h.y = __float2half(w1 * (float)q.y);
    featw[idx] = h;
}

// ---------------- main: per-(pair,vchunk) partial exp-sums ------------------
// grid = (NPAIR_PAD/256, NCHUNK), block = 256. Pair-per-lane; the v-loop row
// loads are block-uniform -> broadcast from L1/L2 (or scalar loads).
__global__ __launch_bounds__(256) void main_kernel(
    const float*   __restrict__ weights,
    const int*     __restrict__ seq,       // B*L ints
    const __half2* __restrict__ featw,
    float*         __restrict__ S2) {      // [NCHUNK][NPAIR_PAD]
    const int tid = threadIdx.x;
    const int P   = blockIdx.x * 256 + tid;
    const int Pc  = (P < NPAIR) ? P : (NPAIR - 1);
    const int b   = Pc / 63;
    const int t   = Pc - b * 63;
    const int p   = seq[b * L_SIZE + t];

    // Build sign row a2[f] = 2*prev_f - 1 (as +-1 in f16) and gp = sum wf*p_f.
    // Sign inferred from featw[p,f] > 0; wrong only when wf==0 where the term
    // is zero anyway.
    __half2 a2[F2];
    float gp = 0.0f;
    const __half  one  = __float2half(1.0f);
    const __half  mone = __float2half(-1.0f);
    const uint4* rp4 = (const uint4*)(featw + (size_t)p * F2);
#pragma unroll
    for (int jj = 0; jj < 32; ++jj) {
        uint4 q = rp4[jj];
        unsigned us[4] = {q.x, q.y, q.z, q.w};
#pragma unroll
        for (int k = 0; k < 4; ++k) {
            __half2 h = u2h(us[k]);
            float hx = h2lo(h), hy = h2hi(h);
            gp += hx + hy;
            __half2 a;
            a.x = (hx > 0.0f) ? one : mone;
            a.y = (hy > 0.0f) ? one : mone;
            a2[4 * jj + k] = a;
        }
    }

    const float kexp = weights[0] * 1.44269504088896340736f;  // w0 * log2(e)
    const __half2 hz = __float2half2_rn(0.0f);
    const __half2* fw0 = featw + (size_t)(blockIdx.y * VCHUNK) * F2;

    float s_acc = 0.0f;
    for (int i = 0; i < VCHUNK; i += 2) {
        const uint4* r0 = (const uint4*)(fw0 + (size_t)i * F2);
        const uint4* r1 = r0 + 32;
        __half2 a0 = hz, a1 = hz, a2a = hz, a3 = hz;   // row i accumulators
        __half2 b0 = hz, b1 = hz, b2 = hz, b3 = hz;    // row i+1 accumulators
#pragma unroll
        for (int j4 = 0; j4 < 32; ++j4) {
            uint4 q0 = r0[j4];
            uint4 q1 = r1[j4];
            a0 = __hfma2(u2h(q0.x), a2[4 * j4 + 0], a0);
            a1 = __hfma2(u2h(q0.y), a2[4 * j4 + 1], a1);
            a2a = __hfma2(u2h(q0.z), a2[4 * j4 + 2], a2a);
            a3 = __hfma2(u2h(q0.w), a2[4 * j4 + 3], a3);
            b0 = __hfma2(u2h(q1.x), a2[4 * j4 + 0], b0);
            b1 = __hfma2(u2h(q1.y), a2[4 * j4 + 1], b1);
            b2 = __hfma2(u2h(q1.z), a2[4 * j4 + 2], b2);
            b3 = __hfma2(u2h(q1.w), a2[4 * j4 + 3], b3);
        }
        __half2 sa = __hadd2(__hadd2(a0, a1), __hadd2(a2a, a3));
        __half2 sb = __hadd2(__hadd2(b0, b1), __hadd2(b2, b3));
        float d0 = h2lo(sa) + h2hi(sa);
        float d1 = h2lo(sb) + h2hi(sb);
        s_acc += exp2f((d0 - gp) * kexp);
        s_acc += exp2f((d1 - gp) * kexp);
    }
    S2[blockIdx.y * NPAIR_PAD + P] = s_acc;   // plain store, no atomics
}

// ---------------- final: nll reduction --------------------------------------
__global__ __launch_bounds__(64) void final_kernel(
    const float*   __restrict__ weights,
    const int*     __restrict__ seq,
    const __half2* __restrict__ featw,
    const float*   __restrict__ S2,
    float*         __restrict__ out) {
    const int P = blockIdx.x * 64 + threadIdx.x;
    float nll = 0.0f;
    if (P < NPAIR) {
        const int b  = P / 63;
        const int t  = P - b * 63;
        const int p  = seq[b * L_SIZE + t];
        const int tg = seq[b * L_SIZE + t + 1];
        const __half2* rp = featw + (size_t)p * F2;
        const __half2* rt = featw + (size_t)tg * F2;
        float gp = 0.0f, xt = 0.0f;
        for (int j = 0; j < F2; ++j) {
            __half2 hp = rp[j], ht = rt[j];
            float px = h2lo(hp), py = h2hi(hp);
            float tx = h2lo(ht), ty = h2hi(ht);
            gp += px + py;
            xt += (px > 0.0f ? tx : -tx) + (py > 0.0f ? ty : -ty);
        }
        float s = 0.0f;
        for (int c = 0; c < NCHUNK; ++c) s += S2[c * NPAIR_PAD + P];
        nll = weights[0] * (gp - xt) + logf(s);
    }
    // wave-64 reduce, one atomic per block
#pragma unroll
    for (int off = 32; off > 0; off >>= 1) nll += __shfl_down(nll, off);
    if (threadIdx.x == 0) atomicAdd(out, nll);
    if (blockIdx.x == 0 && threadIdx.x == 0)
        atomicAdd(out, (float)B_SIZE * logf((float)V_SIZE));  // nll_first
}

extern "C" void kernel_launch(void* const* d_in, const int* in_sizes, int n_in,
                              void* d_out, int out_size, void* d_ws, size_t ws_size,
                              hipStream_t stream) {
    const float* weights  = (const float*)d_in[0];   // 257
    const int*   features = (const int*)d_in[1];     // V*F
    const int*   seq      = (const int*)d_in[2];     // B*L
    float* out = (float*)d_out;

    __half2* featw = (__half2*)d_ws;                                   // 4 MB
    float*   S2    = (float*)((char*)d_ws + (size_t)V_SIZE * F2 * 4);  // 512 KB

    hipMemsetAsync(out, 0, sizeof(float), stream);
    prep_kernel<<<V_SIZE * F2 / 256, 256, 0, stream>>>(weights, features, featw);
    main_kernel<<<dim3(NPAIR_PAD / 256, NCHUNK), 256, 0, stream>>>(weights, seq, featw, S2);
    final_kernel<<<(NPAIR + 63) / 64, 64, 0, stream>>>(weights, seq, featw, S2, out);
}

// Round 2
// 118.008 us; speedup vs baseline: 2.0228x; 2.0228x over previous
//
#include <hip/hip_runtime.h>

// Problem constants (fixed by setup_inputs): V=8192, F=256, B=32, L=64.
#define V_SIZE    8192
#define F_SIZE    256
#define B_SIZE    32
#define L_SIZE    64
#define NPAIR     2016            // B*(L-1)
#define NPAIR_PAD 2048
#define NCHUNK    64              // vocab chunks of 128 (grid.y of main)

// Math: nll = B*ln(V) + sum_pairs [ w0*(g(p) - g(tgt)) + ln(S_pair) ],
//   g(v)   = sum_f wf[f]*feat[v,f]*sign_f,  sign_f = 2*feat[prev,f]-1
//   S_pair = sum_v exp(w0*(g(v) - g(p)))    (g(p) is the EXACT max for wf>=0)
// GEMM form: C = signs[2016x256] @ featw[8192x256]^T  -> bf16 MFMA 32x32x16.

typedef __attribute__((ext_vector_type(8)))  short  short8;   // 8 bf16 = 4 VGPR
typedef __attribute__((ext_vector_type(16))) float  floatx16; // 32x32 acc

__device__ __forceinline__ unsigned short f2bf(float x) {
    union { float f; unsigned u; } c; c.f = x;
    unsigned u = c.u + 0x7FFF + ((c.u >> 16) & 1);   // RNE
    return (unsigned short)(u >> 16);
}
__device__ __forceinline__ float bf2f(unsigned short h) {
    union { unsigned u; float f; } c; c.u = ((unsigned)h) << 16;
    return c.f;
}

// ---------------- prep 1: featw[v,f] = (bf16)(wf[f]*feat[v,f]) --------------
__global__ __launch_bounds__(256) void prep_featw(
    const float* __restrict__ weights,
    const int*   __restrict__ features,
    unsigned short* __restrict__ featw) {
    int idx = (blockIdx.x * 256 + threadIdx.x) * 8;   // 8 elements/thread
    int j = idx & (F_SIZE - 1);
    int4 q0 = *(const int4*)(features + idx);
    int4 q1 = *(const int4*)(features + idx + 4);
    unsigned short r[8];
    r[0] = f2bf(weights[1 + j + 0] * (float)q0.x);
    r[1] = f2bf(weights[1 + j + 1] * (float)q0.y);
    r[2] = f2bf(weights[1 + j + 2] * (float)q0.z);
    r[3] = f2bf(weights[1 + j + 3] * (float)q0.w);
    r[4] = f2bf(weights[1 + j + 4] * (float)q1.x);
    r[5] = f2bf(weights[1 + j + 5] * (float)q1.y);
    r[6] = f2bf(weights[1 + j + 6] * (float)q1.z);
    r[7] = f2bf(weights[1 + j + 7] * (float)q1.w);
    *(uint4*)(featw + idx) = *(const uint4*)r;
}

// ------- prep 2: signs[P,f] = +-1 (bf16), gp[P] = sum_f wf*feat[prev,f] -----
__global__ __launch_bounds__(64) void prep_signs(
    const float* __restrict__ weights,
    const int*   __restrict__ features,
    const int*   __restrict__ seq,
    unsigned short* __restrict__ signs,   // [NPAIR_PAD][F]
    float*       __restrict__ gp) {       // [NPAIR_PAD]
    const int P  = blockIdx.x;                       // 0..2047
    const int Pc = (P < NPAIR) ? P : (NPAIR - 1);
    const int b  = Pc / 63;
    const int t  = Pc - b * 63;
    const int prev = seq[b * L_SIZE + t];
    const int i = threadIdx.x * 4;                   // 4 features/thread
    int4 f = *(const int4*)(features + prev * F_SIZE + i);
    unsigned short s[4];
    s[0] = f.x ? 0x3F80 : 0xBF80;                    // +1 / -1 bf16
    s[1] = f.y ? 0x3F80 : 0xBF80;
    s[2] = f.z ? 0x3F80 : 0xBF80;
    s[3] = f.w ? 0x3F80 : 0xBF80;
    *(ushort4*)(signs + (size_t)P * F_SIZE + i) = *(const ushort4*)s;
    float g = weights[1 + i + 0] * (float)f.x + weights[1 + i + 1] * (float)f.y
            + weights[1 + i + 2] * (float)f.z + weights[1 + i + 3] * (float)f.w;
#pragma unroll
    for (int off = 32; off > 0; off >>= 1) g += __shfl_down(g, off);
    if (threadIdx.x == 0) gp[P] = g;
}

// ---------------- main: MFMA GEMM + fused exp/partial-sum -------------------
// grid (16, 64), block 256 (4 waves). Wave w: pairs [bx*128+w*32, +32),
// cols [by*128, +128). A/B frags loaded straight from global in operand layout.
__global__ __launch_bounds__(256) void main_kernel(
    const float* __restrict__ weights,
    const unsigned short* __restrict__ signs,
    const unsigned short* __restrict__ featw,
    const float* __restrict__ gp,
    float*       __restrict__ S2) {       // [NCHUNK][NPAIR_PAD]
    const int tid  = threadIdx.x;
    const int wave = tid >> 6;
    const int lane = tid & 63;
    const int l31  = lane & 31;
    const int h    = lane >> 5;           // 0/1: k-half selector
    const int Pbase = blockIdx.x * 128 + wave * 32;
    const int nbase = blockIdx.y * 128;

    const unsigned short* arow = signs + (size_t)(Pbase + l31) * F_SIZE + h * 8;
    const unsigned short* brow = featw + (size_t)(nbase + l31) * F_SIZE + h * 8;

    floatx16 acc[4];
#pragma unroll
    for (int t = 0; t < 4; ++t)
#pragma unroll
        for (int r = 0; r < 16; ++r) acc[t][r] = 0.0f;

#pragma unroll 2
    for (int c = 0; c < 16; ++c) {        // K chunks of 16
        short8 af = *(const short8*)(arow + c * 16);
#pragma unroll
        for (int t = 0; t < 4; ++t) {
            short8 bf = *(const short8*)(brow + (size_t)t * 32 * F_SIZE + c * 16);
            acc[t] = __builtin_amdgcn_mfma_f32_32x32x16_bf16(af, bf, acc[t], 0, 0, 0);
        }
    }

    // Epilogue: e = exp2(w0*log2e*(C - gp)); sum over this block's 128 cols.
    const float kexp = weights[0] * 1.44269504088896340736f;
    float gpv[16], part[16];
#pragma unroll
    for (int r = 0; r < 16; ++r) {
        gpv[r]  = gp[Pbase + ((r & 3) + 8 * (r >> 2) + 4 * h)];
        part[r] = 0.0f;
    }
#pragma unroll
    for (int t = 0; t < 4; ++t)
#pragma unroll
        for (int r = 0; r < 16; ++r)
            part[r] += exp2f((acc[t][r] - gpv[r]) * kexp);
    // reduce across the 32 column-lanes (same m lives in same lane-half)
#pragma unroll
    for (int off = 16; off > 0; off >>= 1)
#pragma unroll
        for (int r = 0; r < 16; ++r) part[r] += __shfl_xor(part[r], off);
    if (l31 == 0) {
#pragma unroll
        for (int r = 0; r < 16; ++r)
            S2[blockIdx.y * NPAIR_PAD + Pbase + ((r & 3) + 8 * (r >> 2) + 4 * h)] = part[r];
    }
}

// ---------------- final: nll reduction --------------------------------------
__global__ __launch_bounds__(64) void final_kernel(
    const float* __restrict__ weights,
    const int*   __restrict__ seq,
    const unsigned short* __restrict__ signs,
    const unsigned short* __restrict__ featw,
    const float* __restrict__ gp,
    const float* __restrict__ S2,
    float*       __restrict__ out) {
    const int P = blockIdx.x * 64 + threadIdx.x;
    float nll = 0.0f;
    if (P < NPAIR) {
        const int b  = P / 63;
        const int t  = P - b * 63;
        const int tg = seq[b * L_SIZE + t + 1];
        const uint4* sr = (const uint4*)(signs + (size_t)P  * F_SIZE);
        const uint4* wr = (const uint4*)(featw + (size_t)tg * F_SIZE);
        float xt = 0.0f;
#pragma unroll 4
        for (int j = 0; j < F_SIZE / 8; ++j) {
            uint4 s4 = sr[j], w4 = wr[j];
            const unsigned su[4] = {s4.x, s4.y, s4.z, s4.w};
            const unsigned wu[4] = {w4.x, w4.y, w4.z, w4.w};
#pragma unroll
            for (int k = 0; k < 4; ++k) {
                xt += bf2f((unsigned short)(su[k] & 0xFFFF)) * bf2f((unsigned short)(wu[k] & 0xFFFF));
                xt += bf2f((unsigned short)(su[k] >> 16))    * bf2f((unsigned short)(wu[k] >> 16));
            }
        }
        float s = 0.0f;
        for (int c = 0; c < NCHUNK; ++c) s += S2[c * NPAIR_PAD + P];
        nll = weights[0] * (gp[P] - xt) + logf(s);
    }
#pragma unroll
    for (int off = 32; off > 0; off >>= 1) nll += __shfl_down(nll, off);
    if (threadIdx.x == 0) atomicAdd(out, nll);
    if (blockIdx.x == 0 && threadIdx.x == 0)
        atomicAdd(out, (float)B_SIZE * logf((float)V_SIZE));  // nll_first
}

extern "C" void kernel_launch(void* const* d_in, const int* in_sizes, int n_in,
                              void* d_out, int out_size, void* d_ws, size_t ws_size,
                              hipStream_t stream) {
    const float* weights  = (const float*)d_in[0];   // 257
    const int*   features = (const int*)d_in[1];     // V*F ints {0,1}
    const int*   seq      = (const int*)d_in[2];     // B*L
    float* out = (float*)d_out;

    char* ws = (char*)d_ws;
    unsigned short* featw = (unsigned short*)ws;                         // 4 MB
    unsigned short* signs = (unsigned short*)(ws + (size_t)4 * 1024 * 1024);  // 1 MB
    float*          gp    = (float*)(ws + (size_t)5 * 1024 * 1024);      // 8 KB
    float*          S2    = (float*)(ws + (size_t)5 * 1024 * 1024 + 16384);  // 512 KB

    hipMemsetAsync(out, 0, sizeof(float), stream);
    prep_featw<<<V_SIZE * F_SIZE / 8 / 256, 256, 0, stream>>>(weights, features, featw);
    prep_signs<<<NPAIR_PAD, 64, 0, stream>>>(weights, features, seq, signs, gp);
    main_kernel<<<dim3(NPAIR_PAD / 128, NCHUNK), 256, 0, stream>>>(weights, signs, featw, gp, S2);
    final_kernel<<<(NPAIR + 63) / 64, 64, 0, stream>>>(weights, seq, signs, featw, gp, S2, out);
}

// Round 3
// 117.052 us; speedup vs baseline: 2.0393x; 1.0082x over previous
//
#include <hip/hip_runtime.h>

// Problem constants (fixed by setup_inputs): V=8192, F=256, B=32, L=64.
#define V_SIZE    8192
#define F_SIZE    256
#define B_SIZE    32
#define L_SIZE    64
#define NPAIR     2016            // B*(L-1)
#define NPAIR_PAD 2048
#define NCHUNK    64              // vocab chunks of 128 (grid.y of main)
#define ESTRIDE   512             // shorts per [c] step in packed layout (64 lanes * 8)

// Math: nll = B*ln(V) + sum_pairs [ w0*(g(p) - g(tgt)) + ln(S_pair) ],
//   g(v)   = sum_f wf[f]*feat[v,f]*sign_f,  sign_f = 2*feat[prev,f]-1
//   S_pair = sum_v exp(w0*(g(v) - g(p)))    (g(p) is the EXACT max for wf>=0)
// GEMM: C = signs[2016x256] @ featw[8192x256]^T via v_mfma_f32_32x32x16_bf16.
// A/B are PRE-PACKED in MFMA operand order [rowblk32][c][lane64][8] so the
// K-loop loads are fully coalesced 1 KiB/wave dwordx4 streams.

typedef __attribute__((ext_vector_type(8)))  short  short8;   // 8 bf16 = 4 VGPR
typedef __attribute__((ext_vector_type(16))) float  floatx16; // 32x32 acc

__device__ __forceinline__ unsigned short f2bf(float x) {
    union { float f; unsigned u; } c; c.f = x;
    unsigned u = c.u + 0x7FFF + ((c.u >> 16) & 1);   // RNE
    return (unsigned short)(u >> 16);
}

// -------- prep 1: featw packed: entry gid=((rb*16+c)*64+lane) --------------
__global__ __launch_bounds__(256) void prep_featw(
    const float* __restrict__ weights,
    const int*   __restrict__ features,
    unsigned short* __restrict__ fpack) {
    int gid  = blockIdx.x * 256 + threadIdx.x;       // 0 .. V*F/8-1
    int rb   = gid >> 10;                            // 32-row block
    int rem  = gid & 1023;
    int c    = rem >> 6;                             // K chunk (16 elems)
    int lane = rem & 63;
    int row  = rb * 32 + (lane & 31);
    int f0   = c * 16 + (lane >> 5) * 8;
    const int* src = features + row * F_SIZE + f0;
    int4 q0 = *(const int4*)(src);
    int4 q1 = *(const int4*)(src + 4);
    unsigned short r[8];
    r[0] = f2bf(weights[1 + f0 + 0] * (float)q0.x);
    r[1] = f2bf(weights[1 + f0 + 1] * (float)q0.y);
    r[2] = f2bf(weights[1 + f0 + 2] * (float)q0.z);
    r[3] = f2bf(weights[1 + f0 + 3] * (float)q0.w);
    r[4] = f2bf(weights[1 + f0 + 4] * (float)q1.x);
    r[5] = f2bf(weights[1 + f0 + 5] * (float)q1.y);
    r[6] = f2bf(weights[1 + f0 + 6] * (float)q1.z);
    r[7] = f2bf(weights[1 + f0 + 7] * (float)q1.w);
    *(uint4*)(fpack + (size_t)gid * 8) = *(const uint4*)r;
}

// -------- prep 2: packed signs (+-1 bf16) + gp[P] --------------------------
__global__ __launch_bounds__(64) void prep_signs(
    const float* __restrict__ weights,
    const int*   __restrict__ features,
    const int*   __restrict__ seq,
    unsigned short* __restrict__ spack,   // [64][16][64][8]
    float*       __restrict__ gp) {       // [NPAIR_PAD]
    const int P  = blockIdx.x;                       // 0..2047
    const int Pc = (P < NPAIR) ? P : (NPAIR - 1);
    const int b  = Pc / 63;
    const int t  = Pc - b * 63;
    const int prev = seq[b * L_SIZE + t];
    const int f = threadIdx.x * 4;                   // 4 features/thread
    int4 q = *(const int4*)(features + prev * F_SIZE + f);
    unsigned short s[4];
    s[0] = q.x ? 0x3F80 : 0xBF80;
    s[1] = q.y ? 0x3F80 : 0xBF80;
    s[2] = q.z ? 0x3F80 : 0xBF80;
    s[3] = q.w ? 0x3F80 : 0xBF80;
    // packed address: pb=P>>5, c=f>>4, lane'=(P&31)+32*((f>>3)&1), sub=f&7
    const int pb = P >> 5;
    const int c  = f >> 4;
    const int lp = (P & 31) + 32 * ((f >> 3) & 1);
    *(ushort4*)(spack + ((size_t)(pb * 16 + c) * 64 + lp) * 8 + (f & 7)) = *(const ushort4*)s;
    float g = weights[1 + f + 0] * (float)q.x + weights[1 + f + 1] * (float)q.y
            + weights[1 + f + 2] * (float)q.z + weights[1 + f + 3] * (float)q.w;
#pragma unroll
    for (int off = 32; off > 0; off >>= 1) g += __shfl_down(g, off);
    if (threadIdx.x == 0) gp[P] = g;
}

// -------- main: MFMA GEMM + fused exp/partial-sum --------------------------
// grid (16, 64), block 256 (4 waves). Wave w: pairs [bx*128+w*32, +32),
// cols [by*128, +128). All K-loop loads coalesced from packed layouts.
__global__ __launch_bounds__(256) void main_kernel(
    const float* __restrict__ weights,
    const unsigned short* __restrict__ spack,
    const unsigned short* __restrict__ fpack,
    const float* __restrict__ gp,
    float*       __restrict__ S2) {       // [NPAIR_PAD][NCHUNK]
    const int tid  = threadIdx.x;
    const int wave = tid >> 6;
    const int lane = tid & 63;
    const int l31  = lane & 31;
    const int h    = lane >> 5;
    const int pb   = blockIdx.x * 4 + wave;
    const int Pbase = pb * 32;

    const unsigned short* abase = spack + ((size_t)(pb * 16) * 64 + lane) * 8;
    const unsigned short* bbase = fpack + ((size_t)(blockIdx.y * 64) * 64 + lane) * 8;

    floatx16 acc[4];
#pragma unroll
    for (int t = 0; t < 4; ++t)
#pragma unroll
        for (int r = 0; r < 16; ++r) acc[t][r] = 0.0f;

#pragma unroll 4
    for (int c = 0; c < 16; ++c) {        // K chunks of 16
        short8 af = *(const short8*)(abase + c * ESTRIDE);
#pragma unroll
        for (int t = 0; t < 4; ++t) {
            short8 bf = *(const short8*)(bbase + (t * 16 + c) * ESTRIDE);
            acc[t] = __builtin_amdgcn_mfma_f32_32x32x16_bf16(af, bf, acc[t], 0, 0, 0);
        }
    }

    // Epilogue: exp2(w0*log2e*(C - gp)), sum over this block's 128 cols.
    const float kexp = weights[0] * 1.44269504088896340736f;
    float gpv[16], part[16];
#pragma unroll
    for (int r = 0; r < 16; ++r) {
        gpv[r]  = gp[Pbase + ((r & 3) + 8 * (r >> 2) + 4 * h)];
        part[r] = 0.0f;
    }
#pragma unroll
    for (int t = 0; t < 4; ++t)
#pragma unroll
        for (int r = 0; r < 16; ++r)
            part[r] += exp2f((acc[t][r] - gpv[r]) * kexp);
#pragma unroll
    for (int off = 16; off > 0; off >>= 1)
#pragma unroll
        for (int r = 0; r < 16; ++r) part[r] += __shfl_xor(part[r], off);
    if (l31 == 0) {
#pragma unroll
        for (int r = 0; r < 16; ++r)
            S2[(size_t)(Pbase + ((r & 3) + 8 * (r >> 2) + 4 * h)) * NCHUNK + blockIdx.y] = part[r];
    }
}

// -------- final: wave-per-pair nll reduction -------------------------------
// grid 504 x 256 (4 waves = 4 pairs per block). Lane-parallel loads + shfl.
__global__ __launch_bounds__(256) void final_kernel(
    const float* __restrict__ weights,
    const int*   __restrict__ features,
    const int*   __restrict__ seq,
    const float* __restrict__ S2,
    float*       __restrict__ out) {
    const int tid  = threadIdx.x;
    const int P    = blockIdx.x * 4 + (tid >> 6);    // 0..2015 exactly
    const int lane = tid & 63;
    const int b    = P / 63;
    const int t    = P - b * 63;
    const int prev = seq[b * L_SIZE + t];
    const int tg   = seq[b * L_SIZE + t + 1];

    const int f = lane * 4;
    int4 qp = *(const int4*)(features + prev * F_SIZE + f);
    int4 qt = *(const int4*)(features + tg   * F_SIZE + f);
    float w0v = weights[1 + f + 0], w1v = weights[1 + f + 1];
    float w2v = weights[1 + f + 2], w3v = weights[1 + f + 3];
    // gp = sum wf*prev_f ; xt = sum wf*tgt_f*(2*prev_f-1)
    float gpp = w0v * (float)qp.x + w1v * (float)qp.y + w2v * (float)qp.z + w3v * (float)qp.w;
    float xtp = w0v * (float)qt.x * (float)(2 * qp.x - 1)
              + w1v * (float)qt.y * (float)(2 * qp.y - 1)
              + w2v * (float)qt.z * (float)(2 * qp.z - 1)
              + w3v * (float)qt.w * (float)(2 * qp.w - 1);
    float sp = S2[(size_t)P * NCHUNK + lane];        // coalesced 256B/wave

    float a = gpp, x = xtp, s = sp;
#pragma unroll
    for (int off = 32; off > 0; off >>= 1) {
        a += __shfl_down(a, off);
        x += __shfl_down(x, off);
        s += __shfl_down(s, off);
    }
    if (lane == 0) {
        float nll = weights[0] * (a - x) + logf(s);
        atomicAdd(out, nll);
    }
    if (blockIdx.x == 0 && tid == 0)
        atomicAdd(out, (float)B_SIZE * logf((float)V_SIZE));  // nll_first
}

extern "C" void kernel_launch(void* const* d_in, const int* in_sizes, int n_in,
                              void* d_out, int out_size, void* d_ws, size_t ws_size,
                              hipStream_t stream) {
    const float* weights  = (const float*)d_in[0];   // 257
    const int*   features = (const int*)d_in[1];     // V*F ints {0,1}
    const int*   seq      = (const int*)d_in[2];     // B*L
    float* out = (float*)d_out;

    char* ws = (char*)d_ws;
    unsigned short* fpack = (unsigned short*)ws;                             // 4 MB
    unsigned short* spack = (unsigned short*)(ws + (size_t)4 * 1024 * 1024); // 1 MB
    float*          gp    = (float*)(ws + (size_t)5 * 1024 * 1024);          // 8 KB
    float*          S2    = (float*)(ws + (size_t)5 * 1024 * 1024 + 16384);  // 512 KB

    hipMemsetAsync(out, 0, sizeof(float), stream);
    prep_featw<<<V_SIZE * F_SIZE / 8 / 256, 256, 0, stream>>>(weights, features, fpack);
    prep_signs<<<NPAIR_PAD, 64, 0, stream>>>(weights, features, seq, spack, gp);
    main_kernel<<<dim3(NPAIR_PAD / 128, NCHUNK), 256, 0, stream>>>(weights, spack, fpack, gp, S2);
    final_kernel<<<NPAIR / 4, 256, 0, stream>>>(weights, features, seq, S2, out);
}